// Round 15
// baseline (203.536 us; speedup 1.0000x reference)
//
#include <hip/hip_runtime.h>

#define NSP 32768   // 32*32*32 spatial positions
#define EPS 1e-5f

typedef __attribute__((ext_vector_type(8))) __bf16 bf16x8;
typedef __attribute__((ext_vector_type(4))) float f32x4;
typedef __attribute__((ext_vector_type(2))) float f32x2;
typedef __attribute__((ext_vector_type(8))) unsigned short us8;
typedef __attribute__((ext_vector_type(2))) unsigned short us2;

union U8 { us8 u; bf16x8 b; };

__device__ __forceinline__ unsigned short f2bf(float f) {
    unsigned u = __float_as_uint(f);
    u += 0x7fff + ((u >> 16) & 1);
    return (unsigned short)(u >> 16);
}
__device__ __forceinline__ float bf2f(unsigned short h) {
    return __uint_as_float(((unsigned)h) << 16);
}

// ---------------------------------------------------------------------------
// Weight prep (all 4 weights + zero sums in ONE kernel).
// bf16 pre-swizzled LDS tile images for 128(o) x 64(k) tiles.
// ---------------------------------------------------------------------------
__device__ __forceinline__ void prep_range(
    const float* __restrict__ W, int sO, int sC, int ntk,
    unsigned short* __restrict__ Wsw, int i)
{
    int tile = i >> 13;
    int s = i & 8191;
    int r = s >> 6;
    int byte = (s & 63) << 1;
    int ub = byte ^ ((r & 7) << 4);
    int c = ub >> 4;
    int j = (ub >> 1) & 7;
    int ob = tile / ntk;
    int ks = tile - ob * ntk;
    Wsw[i] = f2bf(W[(ob * 128 + r) * sO + (ks * 64 + c * 8 + j) * sC]);
}

__global__ __launch_bounds__(256) void prep_all(
    const float* __restrict__ qkv_w, const float* __restrict__ proj_w,
    const float* __restrict__ w1, const float* __restrict__ w2,
    unsigned short* __restrict__ qkv_sw, unsigned short* __restrict__ proj_sw,
    unsigned short* __restrict__ w1_sw, unsigned short* __restrict__ w2_sw,
    float* __restrict__ sums)
{
    int bid = blockIdx.x, tid = threadIdx.x;
    if (bid < 192)       prep_range(qkv_w, 128, 1, 2, qkv_sw, bid * 256 + tid);
    else if (bid < 256)  prep_range(proj_w, 128, 1, 2, proj_sw, (bid - 192) * 256 + tid);
    else if (bid < 512)  prep_range(w1, 1, 512, 2, w1_sw, (bid - 256) * 256 + tid);
    else if (bid < 768)  prep_range(w2, 1, 128, 8, w2_sw, (bid - 512) * 256 + tid);
    else { sums[tid] = 0.f; sums[tid + 256] = 0.f; }
}

// ---------------------------------------------------------------------------
// bf16 MFMA GEMM, register-prefetch pipelined.
// XMODE: 0 = fp32 [k][NSP]; 2 = bf16 rows [n][RW]
// OMODE: 1 = bf16 [o][NSP] (+ optional fused channel-stats); 2 = qkvT layout
// ---------------------------------------------------------------------------
template<int BN, int XMODE, int OMODE>
__global__ __launch_bounds__(256) void gemm_mfma(
    const unsigned short* __restrict__ Wsw,
    const void* __restrict__ X,
    const float* __restrict__ bias,
    void* __restrict__ Out,
    float* __restrict__ sums,     // if non-null (OMODE1): fused per-channel s/ss
    int K, int rw)
{
    constexpr int NF = BN / 32;
    constexpr int BCH = BN / 32;
    __shared__ __align__(16) unsigned short smem[8192 + BN * 64];
    unsigned short* Asm = smem;
    unsigned short* Bsm = smem + 8192;
    const int tid  = threadIdx.x;
    const int lane = tid & 63;
    const int wid  = tid >> 6;
    const int wr   = wid >> 1, wc = wid & 1;
    const int n0   = blockIdx.x * BN;
    const int o0   = blockIdx.y << 7;
    const int nk   = K >> 6;

    f32x4 acc[4][NF];
    #pragma unroll
    for (int m = 0; m < 4; ++m)
        #pragma unroll
        for (int n = 0; n < NF; ++n)
            acc[m][n] = (f32x4){0.f, 0.f, 0.f, 0.f};

    const int r  = (BN == 128) ? (tid & 127) : (tid & 63);
    const int kh = (BN == 128) ? (tid >> 7)  : (tid >> 6);

    us8 a_pre[4];
    us8 b_pre[BCH];
    int b_c[BCH];
    #pragma unroll
    for (int i = 0; i < BCH; ++i)
        b_c[i] = (BN == 128) ? (((((r >> 5) + i) & 3) << 1) + kh)
                             : (((((r >> 4) + i) & 1) << 2) + kh);

    auto load_tile = [&](int ks) {
        const char* gbase = (const char*)(Wsw + (size_t)(blockIdx.y * nk + ks) * 8192);
        #pragma unroll
        for (int i = 0; i < 4; ++i)
            a_pre[i] = *(const us8*)(gbase + i * 4096 + tid * 16);
        #pragma unroll
        for (int i = 0; i < BCH; ++i) {
            int c = b_c[i];
            int kb = (ks << 6) + (c << 3);
            us8 bv;
            if (XMODE == 0) {
                const float* xp = (const float*)X + (size_t)kb * NSP + n0 + r;
                #pragma unroll
                for (int j = 0; j < 8; ++j) bv[j] = f2bf(xp[(size_t)j * NSP]);
            } else {
                bv = *(const us8*)((const unsigned short*)X + (size_t)(n0 + r) * rw + kb);
            }
            b_pre[i] = bv;
        }
    };
    auto store_tile = [&]() {
        #pragma unroll
        for (int i = 0; i < 4; ++i)
            *(us8*)((char*)Asm + i * 4096 + tid * 16) = a_pre[i];
        #pragma unroll
        for (int i = 0; i < BCH; ++i) {
            int off = (r << 7) + ((b_c[i] << 4) ^ ((r & 7) << 4));
            *(us8*)((char*)Bsm + off) = b_pre[i];
        }
    };

    load_tile(0);
    store_tile();
    __syncthreads();

    for (int ks = 0; ks < nk; ++ks) {
        if (ks + 1 < nk) load_tile(ks + 1);
        #pragma unroll
        for (int ki = 0; ki < 2; ++ki) {
            bf16x8 af[4], bfr[NF];
            int chunk = (ki << 2) + (lane >> 4);
            #pragma unroll
            for (int m = 0; m < 4; ++m) {
                int row = (wr << 6) + (m << 4) + (lane & 15);
                int off = (row << 7) + ((chunk << 4) ^ ((row & 7) << 4));
                U8 t; t.u = *(const us8*)((const char*)Asm + off);
                af[m] = t.b;
            }
            #pragma unroll
            for (int n = 0; n < NF; ++n) {
                int row = wc * (BN / 2) + (n << 4) + (lane & 15);
                int off = (row << 7) + ((chunk << 4) ^ ((row & 7) << 4));
                U8 t; t.u = *(const us8*)((const char*)Bsm + off);
                bfr[n] = t.b;
            }
            #pragma unroll
            for (int m = 0; m < 4; ++m)
                #pragma unroll
                for (int n = 0; n < NF; ++n)
                    acc[m][n] = __builtin_amdgcn_mfma_f32_16x16x32_bf16(af[m], bfr[n], acc[m][n], 0, 0, 0);
        }
        if (ks + 1 < nk) {
            __syncthreads();
            store_tile();
            __syncthreads();
        }
    }

    if (BN == 128 && OMODE == 2) {
        __syncthreads();
        unsigned short* Wt = smem + (wid << 12);
        #pragma unroll
        for (int m = 0; m < 4; ++m)
            #pragma unroll
            for (int reg = 0; reg < 4; ++reg) {
                int ol = (m << 4) + ((lane >> 4) << 2) + reg;
                float b = bias[o0 + (wr << 6) + ol];
                #pragma unroll
                for (int n = 0; n < NF; ++n) {
                    int cl = (n << 4) + (lane & 15);
                    Wt[ol * 64 + (cl ^ ((ol & 7) << 3))] = f2bf(acc[m][n][reg] + b);
                }
            }
        const int d = lane & 15, coff = lane >> 4;
        unsigned short* O = (unsigned short*)Out;
        #pragma unroll
        for (int go = 0; go < 4; ++go) {
            int g = (wr << 2) + go;
            #pragma unroll
            for (int cc = 0; cc < 16; ++cc) {
                int cl = (cc << 2) + coff;
                int ol = (go << 4) + d;
                unsigned short v = Wt[ol * 64 + (cl ^ ((ol & 7) << 3))];
                size_t idx = ((size_t)((blockIdx.y << 3) + g) * NSP + n0 + (wc << 6) + cl) * 16 + d;
                O[idx] = v;
            }
        }
        return;
    }

    // OMODE 1: bf16 [o][NSP], optional fused per-channel stats
    float vs[4][4][NF];
    #pragma unroll
    for (int m = 0; m < 4; ++m) {
        #pragma unroll
        for (int reg = 0; reg < 4; ++reg) {
            int o = o0 + (wr << 6) + (m << 4) + ((lane >> 4) << 2) + reg;
            float b = bias[o];
            #pragma unroll
            for (int n = 0; n < NF; ++n) {
                int col = n0 + wc * (BN / 2) + (n << 4) + (lane & 15);
                size_t oi = (size_t)o * NSP + col;
                float v = acc[m][n][reg] + b;
                vs[m][reg][n] = v;
                ((unsigned short*)Out)[oi] = f2bf(v);
            }
        }
    }
    if (OMODE == 1 && sums) {
        __syncthreads();
        float* sp = (float*)smem;     // sPart[2][128], ssPart[2][128]
        sp[tid] = 0.f; sp[tid + 256] = 0.f;
        __syncthreads();
        #pragma unroll
        for (int m = 0; m < 4; ++m)
            #pragma unroll
            for (int reg = 0; reg < 4; ++reg) {
                float s = 0.f, ss = 0.f;
                #pragma unroll
                for (int n = 0; n < NF; ++n) {
                    float v = vs[m][reg][n];
                    s += v; ss += v * v;
                }
                #pragma unroll
                for (int k = 1; k < 16; k <<= 1) {
                    s  += __shfl_xor(s, k);
                    ss += __shfl_xor(ss, k);
                }
                if ((lane & 15) == 0) {
                    int o = (wr << 6) + (m << 4) + ((lane >> 4) << 2) + reg;
                    sp[wc * 128 + o] = s;
                    sp[256 + wc * 128 + o] = ss;
                }
            }
        __syncthreads();
        if (tid < 128) {
            atomicAdd(&sums[tid * 2],     sp[tid] + sp[128 + tid]);
            atomicAdd(&sums[tid * 2 + 1], sp[256 + tid] + sp[384 + tid]);
        }
    }
}

// ---------------------------------------------------------------------------
// Fused MLP: t2 = norm(yb) + W2^T relu(W1^T norm(yb) + b1) + b2, + t2 stats.
// ---------------------------------------------------------------------------
__global__ __launch_bounds__(256) void mlp_kernel(
    const unsigned short* __restrict__ w1_sw,
    const unsigned short* __restrict__ w2_sw,
    const unsigned short* __restrict__ yb,      // bf16 [128][NSP]
    const float* __restrict__ sums1,
    const float* __restrict__ b1, const float* __restrict__ b2,
    unsigned short* __restrict__ t2b,           // bf16 [128][NSP]
    float* __restrict__ sums2)
{
    __shared__ __align__(16) unsigned short smem[32768];   // 64 KB
    unsigned short* Asm = smem;              // 32 KB
    unsigned short* Xs  = smem + 16384;      // 16 KB
    unsigned short* Hs  = smem + 24576;      // 16 KB
    const int tid  = threadIdx.x;
    const int lane = tid & 63;
    const int wid  = tid >> 6;
    const int wr   = wid >> 1, wc = wid & 1;
    const int n0   = blockIdx.x << 6;

    // stage X = norm(yb) swizzled
    {
        const int r = tid & 63, q = tid >> 6;
        #pragma unroll
        for (int i = 0; i < 4; ++i) {
            int ch = q + (i << 2);
            int k0 = ch << 3;
            us8 bv;
            #pragma unroll
            for (int j = 0; j < 8; ++j) {
                int k = k0 + j;
                float mmean = sums1[k * 2] * (1.f / NSP);
                float inv = rsqrtf(sums1[k * 2 + 1] * (1.f / NSP) - mmean * mmean + EPS);
                bv[j] = f2bf((bf2f(yb[(size_t)k * NSP + n0 + r]) - mmean) * inv);
            }
            int off = ((ch >> 3) << 13) + (r << 7) + (((ch & 7) << 4) ^ ((r & 7) << 4));
            *(us8*)((char*)Xs + off) = bv;
        }
    }
    __syncthreads();

    f32x4 acc2[4][2];
    #pragma unroll
    for (int m = 0; m < 4; ++m)
        #pragma unroll
        for (int n = 0; n < 2; ++n)
            acc2[m][n] = (f32x4){0.f, 0.f, 0.f, 0.f};

    for (int c = 0; c < 4; ++c) {
        if (c) __syncthreads();
        {
            const char* g = (const char*)(w1_sw + (size_t)c * 16384);
            #pragma unroll
            for (int i = 0; i < 8; ++i)
                *(us8*)((char*)Asm + i * 4096 + tid * 16) = *(const us8*)(g + i * 4096 + tid * 16);
        }
        __syncthreads();
        f32x4 accH[4][2];
        #pragma unroll
        for (int m = 0; m < 4; ++m)
            #pragma unroll
            for (int n = 0; n < 2; ++n)
                accH[m][n] = (f32x4){0.f, 0.f, 0.f, 0.f};
        #pragma unroll
        for (int kt = 0; kt < 2; ++kt) {
            #pragma unroll
            for (int ki = 0; ki < 2; ++ki) {
                int chunk = (ki << 2) + (lane >> 4);
                bf16x8 af[4], bfr[2];
                #pragma unroll
                for (int m = 0; m < 4; ++m) {
                    int row = (wr << 6) + (m << 4) + (lane & 15);
                    int off = (kt << 14) + (row << 7) + ((chunk << 4) ^ ((row & 7) << 4));
                    U8 t; t.u = *(const us8*)((const char*)Asm + off);
                    af[m] = t.b;
                }
                #pragma unroll
                for (int n = 0; n < 2; ++n) {
                    int row = (wc << 5) + (n << 4) + (lane & 15);
                    int off = (kt << 13) + (row << 7) + ((chunk << 4) ^ ((row & 7) << 4));
                    U8 t; t.u = *(const us8*)((const char*)Xs + off);
                    bfr[n] = t.b;
                }
                #pragma unroll
                for (int m = 0; m < 4; ++m)
                    #pragma unroll
                    for (int n = 0; n < 2; ++n)
                        accH[m][n] = __builtin_amdgcn_mfma_f32_16x16x32_bf16(af[m], bfr[n], accH[m][n], 0, 0, 0);
            }
        }
        #pragma unroll
        for (int m = 0; m < 4; ++m)
            #pragma unroll
            for (int reg = 0; reg < 4; ++reg) {
                int ol = (m << 4) + ((lane >> 4) << 2) + reg;
                float bb = b1[(c << 7) + (wr << 6) + ol];
                #pragma unroll
                for (int n = 0; n < 2; ++n) {
                    int row = (wc << 5) + (n << 4) + (lane & 15);
                    float v = fmaxf(accH[m][n][reg] + bb, 0.f);
                    int byte = (wr << 13) + (row << 7) + (((ol >> 3) << 4) ^ ((row & 7) << 4)) + ((ol & 7) << 1);
                    *(unsigned short*)((char*)Hs + byte) = f2bf(v);
                }
            }
        __syncthreads();
        {
            const char* g = (const char*)(w2_sw + (size_t)c * 16384);
            #pragma unroll
            for (int i = 0; i < 8; ++i)
                *(us8*)((char*)Asm + i * 4096 + tid * 16) = *(const us8*)(g + i * 4096 + tid * 16);
        }
        __syncthreads();
        #pragma unroll
        for (int kt = 0; kt < 2; ++kt) {
            #pragma unroll
            for (int ki = 0; ki < 2; ++ki) {
                int chunk = (ki << 2) + (lane >> 4);
                bf16x8 af[4], bfr[2];
                #pragma unroll
                for (int m = 0; m < 4; ++m) {
                    int row = (wr << 6) + (m << 4) + (lane & 15);
                    int off = (kt << 14) + (row << 7) + ((chunk << 4) ^ ((row & 7) << 4));
                    U8 t; t.u = *(const us8*)((const char*)Asm + off);
                    af[m] = t.b;
                }
                #pragma unroll
                for (int n = 0; n < 2; ++n) {
                    int row = (wc << 5) + (n << 4) + (lane & 15);
                    int off = (kt << 13) + (row << 7) + ((chunk << 4) ^ ((row & 7) << 4));
                    U8 t; t.u = *(const us8*)((const char*)Hs + off);
                    bfr[n] = t.b;
                }
                #pragma unroll
                for (int m = 0; m < 4; ++m)
                    #pragma unroll
                    for (int n = 0; n < 2; ++n)
                        acc2[m][n] = __builtin_amdgcn_mfma_f32_16x16x32_bf16(af[m], bfr[n], acc2[m][n], 0, 0, 0);
            }
        }
    }

    // epilogue: t2 = acc2 + b2 + X(normed); fused stats for inorm2
    float vs[4][4][2];
    #pragma unroll
    for (int m = 0; m < 4; ++m)
        #pragma unroll
        for (int reg = 0; reg < 4; ++reg) {
            int o2 = (wr << 6) + (m << 4) + ((lane >> 4) << 2) + reg;
            float bb = b2[o2];
            #pragma unroll
            for (int n = 0; n < 2; ++n) {
                int nl = (wc << 5) + (n << 4) + (lane & 15);
                int xbyte = ((o2 >> 6) << 13) + (nl << 7)
                          + ((((o2 & 63) >> 3) << 4) ^ ((nl & 7) << 4)) + ((o2 & 7) << 1);
                float resid = bf2f(*(const unsigned short*)((const char*)Xs + xbyte));
                float v = acc2[m][n][reg] + bb + resid;
                vs[m][reg][n] = v;
                t2b[(size_t)o2 * NSP + n0 + nl] = f2bf(v);
            }
        }
    __syncthreads();
    float* sp = (float*)smem;
    sp[tid] = 0.f; sp[tid + 256] = 0.f;
    __syncthreads();
    #pragma unroll
    for (int m = 0; m < 4; ++m)
        #pragma unroll
        for (int reg = 0; reg < 4; ++reg) {
            float s = 0.f, ss = 0.f;
            #pragma unroll
            for (int n = 0; n < 2; ++n) {
                float v = vs[m][reg][n];
                s += v; ss += v * v;
            }
            #pragma unroll
            for (int k = 1; k < 16; k <<= 1) {
                s  += __shfl_xor(s, k);
                ss += __shfl_xor(ss, k);
            }
            if ((lane & 15) == 0) {
                int o2 = (wr << 6) + (m << 4) + ((lane >> 4) << 2) + reg;
                sp[wc * 128 + o2] = s;
                sp[256 + wc * 128 + o2] = ss;
            }
        }
    __syncthreads();
    if (tid < 128) {
        atomicAdd(&sums2[tid * 2],     sp[tid] + sp[128 + tid]);
        atomicAdd(&sums2[tid * 2 + 1], sp[256 + tid] + sp[384 + tid]);
    }
}

// ---------------------------------------------------------------------------
// Halo-LDS neighborhood attention. Block = (4h,4w,32z) tile x 1 group,
// 512 threads. K/V halo (6,6,32) staged in LDS (z-swizzled), rpb in LDS.
// ---------------------------------------------------------------------------
__global__ __launch_bounds__(512) void attn_kernel(
    const unsigned short* __restrict__ qkvT, const float* __restrict__ rpb,
    unsigned short* __restrict__ samT)
{
    __shared__ __align__(16) unsigned short KV[36864];   // K 36 KB + V 36 KB
    __shared__ float rps[125];
    const int g = blockIdx.y;
    const int h0 = (blockIdx.x >> 3) << 2;
    const int w0 = (blockIdx.x & 7) << 2;
    const int tid = threadIdx.x;

    if (tid < 125) rps[tid] = rpb[g * 125 + tid];

    // stage K/V halo: 36 rows x 64 us8 per part
    for (int i = tid; i < 4608; i += 512) {
        int part = (i >= 2304) ? 1 : 0;
        int rem = i - part * 2304;
        int row = rem >> 6;
        int v8 = rem & 63;
        int hh = row / 6, ww = row - hh * 6;
        int hg = min(max(h0 - 1 + hh, 0), 31);
        int wg = min(max(w0 - 1 + ww, 0), 31);
        const us8* src = (const us8*)(qkvT + ((size_t)((1 + part) * 8 + g) * NSP
                         + (hg << 10) + (wg << 5)) * 16);
        int zz = v8 >> 1;
        int byte = (((row << 10) + (v8 << 4)) ^ ((zz & 4) << 2)) + part * 36864;
        *(us8*)((char*)KV + byte) = src[v8];
    }

    const int lh = tid >> 7, lw = (tid >> 5) & 3, z = tid & 31;
    const int h = h0 + lh, w = w0 + lw;
    const int n = (h << 10) + (w << 5) + z;
    const int ih0 = min(max(h - 1, 0), 29);
    const int iw0 = min(max(w - 1, 0), 29);
    const int iz0 = min(max(z - 1, 0), 29);
    const int lh0 = ih0 - h0 + 1;   // 0..3
    const int lw0 = iw0 - w0 + 1;   // 0..3

    float q[16];
    {
        const us8* qp = (const us8*)(qkvT + ((size_t)g * NSP + n) * 16);
        us8 q0 = qp[0], q1 = qp[1];
        #pragma unroll
        for (int j = 0; j < 8; ++j) { q[j] = bf2f(q0[j]); q[8 + j] = bf2f(q1[j]); }
    }
    __syncthreads();

    float logits[27];
    int idx = 0;
    #pragma unroll
    for (int kh = 0; kh < 3; ++kh)
    #pragma unroll
    for (int kw = 0; kw < 3; ++kw) {
        int lr = (lh0 + kh) * 6 + (lw0 + kw);
        #pragma unroll
        for (int kz = 0; kz < 3; ++kz) {
            int zz = iz0 + kz;
            int b0 = (((lr << 10) + (zz << 5)) ^ ((zz & 4) << 2));
            int b1 = (((lr << 10) + (zz << 5) + 16) ^ ((zz & 4) << 2));
            us8 k0 = *(const us8*)((const char*)KV + b0);
            us8 k1 = *(const us8*)((const char*)KV + b1);
            float s = 0.f;
            #pragma unroll
            for (int j = 0; j < 8; ++j) s += q[j] * bf2f(k0[j]);
            #pragma unroll
            for (int j = 0; j < 8; ++j) s += q[8 + j] * bf2f(k1[j]);
            int rh = ih0 + kh - h + 2, rw = iw0 + kw - w + 2, rz = zz - z + 2;
            logits[idx++] = s * 0.25f + rps[rh * 25 + rw * 5 + rz];
        }
    }

    float mx = -1e30f;
    #pragma unroll
    for (int i = 0; i < 27; ++i) mx = fmaxf(mx, logits[i]);
    float sum = 0.f;
    #pragma unroll
    for (int i = 0; i < 27; ++i) { logits[i] = __expf(logits[i] - mx); sum += logits[i]; }
    float inv = 1.f / sum;

    float o[16] = {};
    idx = 0;
    #pragma unroll
    for (int kh = 0; kh < 3; ++kh)
    #pragma unroll
    for (int kw = 0; kw < 3; ++kw) {
        int lr = (lh0 + kh) * 6 + (lw0 + kw);
        #pragma unroll
        for (int kz = 0; kz < 3; ++kz) {
            int zz = iz0 + kz;
            int b0 = (((lr << 10) + (zz << 5)) ^ ((zz & 4) << 2)) + 36864;
            int b1 = (((lr << 10) + (zz << 5) + 16) ^ ((zz & 4) << 2)) + 36864;
            us8 v0 = *(const us8*)((const char*)KV + b0);
            us8 v1 = *(const us8*)((const char*)KV + b1);
            float a = logits[idx++] * inv;
            #pragma unroll
            for (int j = 0; j < 8; ++j) { o[j] += a * bf2f(v0[j]); o[8 + j] += a * bf2f(v1[j]); }
        }
    }
    us8 o0v, o1v;
    #pragma unroll
    for (int j = 0; j < 8; ++j) { o0v[j] = f2bf(o[j]); o1v[j] = f2bf(o[8 + j]); }
    us8* op = (us8*)(samT + (size_t)n * 128 + g * 16);
    op[0] = o0v; op[1] = o1v;
}

// ---------------------------------------------------------------------------
// Fused: inorm2 apply (bf16 in) + skip add (fp32 x) + 2x2x2 maxpool.
// ---------------------------------------------------------------------------
__global__ __launch_bounds__(256) void inorm_skip_pool(
    const unsigned short* __restrict__ t2, const float* __restrict__ x,
    const float* __restrict__ sums,
    float* __restrict__ skip, float* __restrict__ down)
{
    int m = blockIdx.x * 256 + threadIdx.x;
    int c = m >> 12;
    int r = m & 4095;
    int oh = r >> 8, ow = (r >> 4) & 15, oz = r & 15;
    float mean = sums[c * 2] * (1.f / NSP);
    float inv = rsqrtf(sums[c * 2 + 1] * (1.f / NSP) - mean * mean + EPS);
    size_t base = (size_t)c * NSP + oh * 2048 + ow * 64 + oz * 2;
    float mx = -1e30f;
    #pragma unroll
    for (int dh = 0; dh < 2; ++dh)
    #pragma unroll
    for (int dw = 0; dw < 2; ++dw) {
        size_t a = base + dh * 1024 + dw * 32;
        us2 tv = *(const us2*)(t2 + a);
        f32x2 xv = *(const f32x2*)(x + a);
        f32x2 sv;
        sv.x = (bf2f(tv.x) - mean) * inv + xv.x;
        sv.y = (bf2f(tv.y) - mean) * inv + xv.y;
        *(f32x2*)(skip + a) = sv;
        mx = fmaxf(mx, fmaxf(sv.x, sv.y));
    }
    down[m] = mx;
}

// ---------------------------------------------------------------------------
extern "C" void kernel_launch(void* const* d_in, const int* in_sizes, int n_in,
                              void* d_out, int out_size, void* d_ws, size_t ws_size,
                              hipStream_t stream)
{
    const float* x      = (const float*)d_in[0];
    const float* qkv_w  = (const float*)d_in[1];
    const float* qkv_b  = (const float*)d_in[2];
    const float* proj_w = (const float*)d_in[3];
    const float* proj_b = (const float*)d_in[4];
    const float* rpb    = (const float*)d_in[5];
    const float* w1     = (const float*)d_in[6];
    const float* b1     = (const float*)d_in[7];
    const float* w2     = (const float*)d_in[8];
    const float* b2     = (const float*)d_in[9];

    float* out  = (float*)d_out;
    float* down = out;              // 2 MB, dead until final kernel
    float* skip = out + 524288;

    unsigned short* wb      = (unsigned short*)d_out;
    unsigned short* qkv_sw  = wb;
    unsigned short* proj_sw = wb + 49152;
    unsigned short* w1_sw   = wb + 65536;
    unsigned short* w2_sw   = wb + 131072;

    char* ws = (char*)d_ws;
    const size_t MB = 1u << 20;
    unsigned short* qkvT = (unsigned short*)(ws);            //  0..24 MB
    unsigned short* samT = (unsigned short*)(ws + 24 * MB);  // 24..32 MB [n][128]
    unsigned short* yb   = (unsigned short*)(ws + 32 * MB);  // 32..40 MB [c][n]
    unsigned short* t2b  = (unsigned short*)(ws + 48 * MB);  // 48..56 MB [c][n]
    float*          sums = (float*)(ws + 72 * MB);           // 512 floats
    float* sums1 = sums;
    float* sums2 = sums + 256;

    // 0) weight prep + zero sums
    prep_all<<<769, 256, 0, stream>>>(qkv_w, proj_w, w1, w2,
                                      qkv_sw, proj_sw, w1_sw, w2_sw, sums);
    // 1) qkv -> qkvT
    gemm_mfma<128, 0, 2><<<dim3(256, 3), 256, 0, stream>>>(
        qkv_sw, x, qkv_b, qkvT, nullptr, 128, 0);
    // 2) halo-LDS attention -> samT
    attn_kernel<<<dim3(64, 8), 512, 0, stream>>>(qkvT, rpb, samT);
    // 3) proj -> yb, fused inorm1 stats
    gemm_mfma<64, 2, 1><<<dim3(512, 1), 256, 0, stream>>>(
        proj_sw, samT, proj_b, yb, sums1, 128, 128);
    // 4) fused MLP -> t2b, fused inorm2 stats
    mlp_kernel<<<512, 256, 0, stream>>>(w1_sw, w2_sw, yb, sums1, b1, b2, t2b, sums2);
    // 5) fused inorm2 apply + skip + maxpool
    inorm_skip_pool<<<2048, 256, 0, stream>>>(t2b, x, sums2, skip, down);
}